// Round 13
// baseline (991.371 us; speedup 1.0000x reference)
//
#include <hip/hip_runtime.h>
#include <cstdint>
#include <cstddef>

// Bidirectional 3-layer tanh RNN, S=512 B=512 D=300 H=256.
// R13: gemm0 reverted to R9 form but split per-chunk and CO-SCHEDULED inside
//      the rec slot launches (grid = 192 rec + 128 gemm0 blocks; chunk s+1
//      produced at slot s, consumed at slot s+1 via launch boundary).
//      rec = R12 (unroll-4 z prefetch) + 8-way MFMA chain split for L<2.

#define SEQ   512
#define BATCH 512
#define DIN   300
#define HDIM  256
#define NT    512
#define CH    64
#define NCH   (SEQ / CH)    // 8
#define TS    16
#define ZTILE 131072        // u16 per (d,t) tile (512 rows x 256 cols)
#define XLBUF 5312          // u16 per gemm0 LDS x-buffer (16*332)

typedef _Float16 f16x8 __attribute__((ext_vector_type(8)));
typedef __fp16   fp16x2 __attribute__((ext_vector_type(2)));
typedef float    f32x4 __attribute__((ext_vector_type(4)));

// ---- ws layout ----
#define WIH0_E 0            // f16 [2 dir][16ct][10kt][64][8]
#define WHH_E  163840       // f16 [2][3 layer][16ct][8kt][64][8]
#define WIHN_E 557056       // f16 [2][2 (->l1,l2)][16ct][8kt][64][8]
#define HC_BYTE   1638400   // u16 [2d][3l][512][256]
#define HB_BYTE   3211264
#define Z0_BYTE   (HB_BYTE + 67108864)
#define Z1_BYTE   (Z0_BYTE + 268435456)
#define Z2_BYTE   (Z1_BYTE + 67108864)
#define RING_E    8388608ull   // u16 per ring region (CH tiles)

static __device__ __forceinline__ uint16_t f16bits(_Float16 h) {
    union { _Float16 h; uint16_t u; } v; v.h = h; return v.u;
}
static __device__ __forceinline__ uint32_t pk2(float a, float b) {
    union { fp16x2 h; uint32_t u; } v; v.h = __builtin_amdgcn_cvt_pkrtz(a, b); return v.u;
}
static __device__ __forceinline__ int swz(int row, int col) {   // u16-index swizzle
    return (row * 256 + col) ^ ((row & 7) << 3);
}

// 8 fragment loads in one volatile asm (results CANNOT be rematerialized).
static __device__ __forceinline__ void aload8(f16x8 r[8], const _Float16* p, size_t stepE) {
    const _Float16* p0 = p;
    const _Float16* p1 = p + stepE;
    const _Float16* p2 = p + 2 * stepE;
    const _Float16* p3 = p + 3 * stepE;
    const _Float16* p4 = p + 4 * stepE;
    const _Float16* p5 = p + 5 * stepE;
    const _Float16* p6 = p + 6 * stepE;
    const _Float16* p7 = p + 7 * stepE;
    asm volatile(
        "global_load_dwordx4 %0, %8, off\n\t"
        "global_load_dwordx4 %1, %9, off\n\t"
        "global_load_dwordx4 %2, %10, off\n\t"
        "global_load_dwordx4 %3, %11, off\n\t"
        "global_load_dwordx4 %4, %12, off\n\t"
        "global_load_dwordx4 %5, %13, off\n\t"
        "global_load_dwordx4 %6, %14, off\n\t"
        "global_load_dwordx4 %7, %15, off"
        : "=&v"(r[0]), "=&v"(r[1]), "=&v"(r[2]), "=&v"(r[3]),
          "=&v"(r[4]), "=&v"(r[5]), "=&v"(r[6]), "=&v"(r[7])
        : "v"(p0), "v"(p1), "v"(p2), "v"(p3), "v"(p4), "v"(p5), "v"(p6), "v"(p7)
        : "memory");
}
static __device__ __forceinline__ void adrain() {
    asm volatile("s_waitcnt vmcnt(0)" ::: "memory");
    __builtin_amdgcn_sched_barrier(0);
}

// ---------------- prep: weights -> f16 fragment layout ----------------
__global__ void rnn_prep(const float* __restrict__ fW_ih0, const float* __restrict__ fW_ih,
                         const float* __restrict__ fW_hh,  const float* __restrict__ bW_ih0,
                         const float* __restrict__ bW_ih,  const float* __restrict__ bW_hh,
                         _Float16* __restrict__ wf)
{
    const int gid = blockIdx.x * 256 + threadIdx.x;   // 0..102399
    const int d = gid / 51200;
    const int r = gid - d * 51200;
    const int lane = r & 63;
    const float* Wih0 = d ? bW_ih0 : fW_ih0;
    const float* Wih  = d ? bW_ih  : fW_ih;
    const float* Whh  = d ? bW_hh  : fW_hh;
    _Float16 vals[8];
    size_t dstE;
    if (r < 10240) {                       // W_ih0 frags, K=320 padded
        const int ck = r >> 6, ct = ck / 10, kt = ck - ct * 10;
        const int col = ct * 16 + (lane & 15);
        const int k0  = kt * 32 + (lane >> 4) * 8;
        #pragma unroll
        for (int e = 0; e < 8; ++e) {
            const int k = k0 + e;
            vals[e] = (k < 300) ? (_Float16)Wih0[(size_t)k * 256 + col] : (_Float16)0.f;
        }
        dstE = (size_t)WIH0_E + (size_t)d * 81920 + (size_t)r * 8;
    } else if (r < 34816) {                // W_hh frags
        const int rr = r - 10240, l = rr / 8192, r2 = rr - l * 8192;
        const int ck = r2 >> 6, ct = ck >> 3, kt = ck & 7;
        const int col = ct * 16 + (lane & 15);
        const int k0  = kt * 32 + (lane >> 4) * 8;
        #pragma unroll
        for (int e = 0; e < 8; ++e)
            vals[e] = (_Float16)Whh[((size_t)(l * 256 + k0 + e)) * 256 + col];
        dstE = (size_t)WHH_E + (size_t)(d * 3 + l) * 65536 + (size_t)r2 * 8;
    } else {                               // W_ih layers 1,2 frags
        const int rr = r - 34816, ln = rr / 8192, r2 = rr - ln * 8192;
        const int ck = r2 >> 6, ct = ck >> 3, kt = ck & 7;
        const int col = ct * 16 + (lane & 15);
        const int k0  = kt * 32 + (lane >> 4) * 8;
        #pragma unroll
        for (int e = 0; e < 8; ++e)
            vals[e] = (_Float16)Wih[((size_t)(ln * 256 + k0 + e)) * 256 + col];
        dstE = (size_t)WIHN_E + (size_t)(d * 2 + ln) * 65536 + (size_t)r2 * 8;
    }
    *(f16x8*)(wf + dstE) = *(const f16x8*)vals;
}

// ---------------- gemm0 chunk (R9 form): Zin0 = x @ W_ih0 + b0 ----------------
// gb in [0,128): sg4 = gb>>5 (16-timestep group within chunk), rb = gb&31 (16 rows).
__device__ __forceinline__ void gemm0_chunk(const float* __restrict__ x,
                                            const _Float16* __restrict__ wih0,
                                            const float* __restrict__ fb,
                                            const float* __restrict__ bb,
                                            uint16_t* __restrict__ z0,
                                            int chunk, int gb, uint16_t* Xl)
{
    const int tid = threadIdx.x, lane = tid & 63, w = tid >> 6;
    const int colw = lane & 15, rq = lane >> 4, rq8 = rq * 8;
    const int ct0 = w * 2;
    const int sg4 = gb >> 5, rb = gb & 31;
    const int b0 = rb * 16;
    const int sbase = chunk * CH + sg4 * TS;
    const size_t chunkoff = ((size_t)(rb * 8 + w) * 64 + lane) * 8;

    int rs[5], cc2[5]; bool pv[5];
    #pragma unroll
    for (int b = 0; b < 5; ++b) {
        const int p = tid + b * NT;
        pv[b] = p < 2400;                  // 16 rows x 150 float2
        const int r = p / 150;
        rs[b] = r; cc2[b] = (p - r * 150) * 2;
    }

    float bv[2][2];
    #pragma unroll
    for (int dd = 0; dd < 2; ++dd)
        #pragma unroll
        for (int c = 0; c < 2; ++c)
            bv[dd][c] = (dd ? bb : fb)[(ct0 + c) * 16 + colw];

    for (int p = tid; p < 320; p += NT) {  // zero pad k in [300,320), both buffers
        const int bu = p / 160, q = p - bu * 160;
        const int r = q / 10, cc = 300 + (q - r * 10) * 2;
        *(uint32_t*)&Xl[bu * XLBUF + r * 332 + cc] = 0;
    }
    {   // stage si=0
        const float* xs = x + ((size_t)sbase * BATCH + b0) * DIN;
        #pragma unroll
        for (int b = 0; b < 5; ++b) if (pv[b]) {
            const float2 v = *(const float2*)(xs + (size_t)rs[b] * DIN + cc2[b]);
            *(uint32_t*)&Xl[rs[b] * 332 + cc2[b]] = pk2(v.x, v.y);
        }
    }
    __syncthreads();

    #pragma unroll 1
    for (int si = 0; si < TS; ++si) {
        const int s = sbase + si;
        const int buf = si & 1;
        const bool last = (si == TS - 1);

        {   // dir 0
            f32x4 a0 = (f32x4){bv[0][0], bv[0][0], bv[0][0], bv[0][0]};
            f32x4 a1 = (f32x4){bv[0][1], bv[0][1], bv[0][1], bv[0][1]};
            #pragma unroll
            for (int kt = 0; kt < 10; ++kt) {
                const f16x8 wv0 = *(const f16x8*)(wih0 + (((size_t)ct0 * 10 + kt) * 64 + lane) * 8);
                const f16x8 wv1 = *(const f16x8*)(wih0 + (((size_t)(ct0 + 1) * 10 + kt) * 64 + lane) * 8);
                const f16x8 a = *(const f16x8*)&Xl[buf * XLBUF + colw * 332 + kt * 32 + rq8];
                a0 = __builtin_amdgcn_mfma_f32_16x16x32_f16(a, wv0, a0, 0, 0, 0);
                a1 = __builtin_amdgcn_mfma_f32_16x16x32_f16(a, wv1, a1, 0, 0, 0);
            }
            uint4 sv;
            sv.x = pk2(a0[0], a0[1]); sv.y = pk2(a0[2], a0[3]);
            sv.z = pk2(a1[0], a1[1]); sv.w = pk2(a1[2], a1[3]);
            *(uint4*)(z0 + (size_t)s * ZTILE + chunkoff) = sv;
        }

        float2 xr[5];
        if (!last) {
            const float* xs = x + ((size_t)(s + 1) * BATCH + b0) * DIN;
            #pragma unroll
            for (int b = 0; b < 5; ++b) if (pv[b])
                xr[b] = *(const float2*)(xs + (size_t)rs[b] * DIN + cc2[b]);
        }

        {   // dir 1
            f32x4 a0 = (f32x4){bv[1][0], bv[1][0], bv[1][0], bv[1][0]};
            f32x4 a1 = (f32x4){bv[1][1], bv[1][1], bv[1][1], bv[1][1]};
            #pragma unroll
            for (int kt = 0; kt < 10; ++kt) {
                const f16x8 wv0 = *(const f16x8*)(wih0 + 81920 + (((size_t)ct0 * 10 + kt) * 64 + lane) * 8);
                const f16x8 wv1 = *(const f16x8*)(wih0 + 81920 + (((size_t)(ct0 + 1) * 10 + kt) * 64 + lane) * 8);
                const f16x8 a = *(const f16x8*)&Xl[buf * XLBUF + colw * 332 + kt * 32 + rq8];
                a0 = __builtin_amdgcn_mfma_f32_16x16x32_f16(a, wv0, a0, 0, 0, 0);
                a1 = __builtin_amdgcn_mfma_f32_16x16x32_f16(a, wv1, a1, 0, 0, 0);
            }
            uint4 sv;
            sv.x = pk2(a0[0], a0[1]); sv.y = pk2(a0[2], a0[3]);
            sv.z = pk2(a1[0], a1[1]); sv.w = pk2(a1[2], a1[3]);
            *(uint4*)(z0 + ((size_t)SEQ + (SEQ - 1 - s)) * ZTILE + chunkoff) = sv;
        }

        if (!last) {
            #pragma unroll
            for (int b = 0; b < 5; ++b) if (pv[b])
                *(uint32_t*)&Xl[(buf ^ 1) * XLBUF + rs[b] * 332 + cc2[b]] = pk2(xr[b].x, xr[b].y);
        }

        __builtin_amdgcn_sched_barrier(0);
        asm volatile("s_waitcnt lgkmcnt(0)" ::: "memory");
        __builtin_amdgcn_s_barrier();
        __builtin_amdgcn_sched_barrier(0);
    }
}

// ---------------- fused rec<L>: unroll-4 z prefetch, 8-chain MFMA ----------------
template<int L>
__device__ __forceinline__ void rec_run(const _Float16* whh_all, const _Float16* wihn_all,
                                        const uint16_t* zsrc, uint16_t* zdst,
                                        uint16_t* hcarry, const float* fb, const float* bb,
                                        float* out, int d, int i, int cs, uint16_t* Hb)
{
    const int tid = threadIdx.x, lane = tid & 63, w = tid >> 6;
    const int colw = lane & 15, rq = lane >> 4, rq8 = rq * 8;
    const int ct0 = w * 2;
    const int grow0 = i * 16;

    // ---- weights: asm-pinned, single drain ----
    const _Float16* whh = whh_all + (size_t)(d * 3 + L) * 65536;
    f16x8 wh0[8], wh1[8];
    aload8(wh0, whh + ((size_t)ct0 * 8 * 64 + lane) * 8, 512);
    aload8(wh1, whh + ((size_t)(ct0 + 1) * 8 * 64 + lane) * 8, 512);
    f16x8 wn0[8], wn1[8];
    float bn0 = 0.f, bn1 = 0.f;
    if constexpr (L < 2) {
        const _Float16* wnx = wihn_all + (size_t)(d * 2 + L) * 65536;
        aload8(wn0, wnx + ((size_t)ct0 * 8 * 64 + lane) * 8, 512);
        aload8(wn1, wnx + ((size_t)(ct0 + 1) * 8 * 64 + lane) * 8, 512);
        const float* bnx = (d ? bb : fb) + (L + 1) * HDIM;
        bn0 = bnx[ct0 * 16 + colw];
        bn1 = bnx[(ct0 + 1) * 16 + colw];
    }
    adrain();

    // ---- init h LDS (zero; carry into buffer 1, swizzled) ----
    for (int p = tid; p < 4096; p += NT) ((uint32_t*)Hb)[p] = 0;
    __syncthreads();
    if (cs > 0) {
        const uint16_t* hc = hcarry + (size_t)(d * 3 + L) * 131072;
        const int row = tid >> 5, c8 = (tid & 31) * 8;
        *(uint4*)&Hb[4096 + ((row * 256 + c8) ^ ((row & 7) << 3))] =
            *(const uint4*)(hc + (size_t)(grow0 + row) * 256 + c8);
    }
    __syncthreads();

    const size_t zoff = ((size_t)(i * 8 + w) * 64 + lane) * 8;

    uint4 zp[4];
    #pragma unroll
    for (int j = 0; j < 4; ++j)
        zp[j] = *(const uint4*)(zsrc + (size_t)j * ZTILE + zoff);

    f32x4 anp0 = {}, anp1 = {};

    #pragma unroll 1
    for (int k0 = 0; k0 < CH; k0 += 4) {
        #pragma unroll
        for (int u = 0; u < 4; ++u) {
            const int k = k0 + u;
            const int cur = u & 1, prv = cur ^ 1;

            // C-init = z(k) (loaded 4 sub-steps ago)
            f32x4 ar0a, ar1a;
            {
                union { uint4 v; _Float16 h[8]; } zz; zz.v = zp[u];
                ar0a = (f32x4){(float)zz.h[0], (float)zz.h[1], (float)zz.h[2], (float)zz.h[3]};
                ar1a = (f32x4){(float)zz.h[4], (float)zz.h[5], (float)zz.h[6], (float)zz.h[7]};
            }
            {   // reload for k+4
                const int kp = (k + 4 < CH) ? (k + 4) : (CH - 1);
                zp[u] = *(const uint4*)(zsrc + (size_t)kp * ZTILE + zoff);
            }

            f16x8 ah[8];
            #pragma unroll
            for (int kt = 0; kt < 8; ++kt)
                ah[kt] = *(const f16x8*)&Hb[(prv << 12) + swz(colw, kt * 32 + rq8)];

            f32x4 ar0, ar1, an0, an1;
            if constexpr (L < 2) {
                f32x4 ar0b = {}, ar1b = {};
                f32x4 an0a = (f32x4){bn0, bn0, bn0, bn0}, an0b = {};
                f32x4 an1a = (f32x4){bn1, bn1, bn1, bn1}, an1b = {};
                #pragma unroll
                for (int kt = 0; kt < 4; ++kt) {       // 8 chains x 4 deep
                    ar0a = __builtin_amdgcn_mfma_f32_16x16x32_f16(ah[kt],     wh0[kt],     ar0a, 0, 0, 0);
                    ar1a = __builtin_amdgcn_mfma_f32_16x16x32_f16(ah[kt],     wh1[kt],     ar1a, 0, 0, 0);
                    an0a = __builtin_amdgcn_mfma_f32_16x16x32_f16(ah[kt],     wn0[kt],     an0a, 0, 0, 0);
                    an1a = __builtin_amdgcn_mfma_f32_16x16x32_f16(ah[kt],     wn1[kt],     an1a, 0, 0, 0);
                    ar0b = __builtin_amdgcn_mfma_f32_16x16x32_f16(ah[4 + kt], wh0[4 + kt], ar0b, 0, 0, 0);
                    ar1b = __builtin_amdgcn_mfma_f32_16x16x32_f16(ah[4 + kt], wh1[4 + kt], ar1b, 0, 0, 0);
                    an0b = __builtin_amdgcn_mfma_f32_16x16x32_f16(ah[4 + kt], wn0[4 + kt], an0b, 0, 0, 0);
                    an1b = __builtin_amdgcn_mfma_f32_16x16x32_f16(ah[4 + kt], wn1[4 + kt], an1b, 0, 0, 0);
                }
                ar0 = ar0a + ar0b; ar1 = ar1a + ar1b;
                an0 = an0a + an0b; an1 = an1a + an1b;
            } else {
                f32x4 arB0 = {}, arB1 = {};
                #pragma unroll
                for (int kt = 0; kt < 4; ++kt) {
                    ar0a = __builtin_amdgcn_mfma_f32_16x16x32_f16(ah[kt],     wh0[kt],     ar0a, 0, 0, 0);
                    ar1a = __builtin_amdgcn_mfma_f32_16x16x32_f16(ah[kt],     wh1[kt],     ar1a, 0, 0, 0);
                    arB0 = __builtin_amdgcn_mfma_f32_16x16x32_f16(ah[4 + kt], wh0[4 + kt], arB0, 0, 0, 0);
                    arB1 = __builtin_amdgcn_mfma_f32_16x16x32_f16(ah[4 + kt], wh1[4 + kt], arB1, 0, 0, 0);
                }
                ar0 = ar0a + arB0;
                ar1 = ar1a + arB1;
                an0 = an0; an1 = an1;   // unused
            }

            // emit Zin_next(k-2) in the MFMA shadow
            if constexpr (L < 2) {
                if (k >= 2) {
                    uint4 sv;
                    sv.x = pk2(anp0[0], anp0[1]); sv.y = pk2(anp0[2], anp0[3]);
                    sv.z = pk2(anp1[0], anp1[1]); sv.w = pk2(anp1[2], anp1[3]);
                    *(uint4*)(zdst + (size_t)(k - 2) * ZTILE + zoff) = sv;
                }
            }

            float hv[8];
            #pragma unroll
            for (int q = 0; q < 8; ++q) {
                const float S = (q < 4) ? ar0[q] : ar1[q - 4];
                const float e = __builtin_amdgcn_exp2f(S * 2.885390081777927f);
                const float r = __builtin_amdgcn_rcpf(e + 1.f);
                hv[q] = __builtin_fmaf(-2.f, r, 1.f);
            }
            #pragma unroll
            for (int q = 0; q < 8; ++q) {
                const int c = q >> 2, j = q & 3;
                Hb[(cur << 12) + swz(rq * 4 + j, (ct0 + c) * 16 + colw)] = f16bits((_Float16)hv[q]);
            }
            if (L == 2 && cs == NCH - 1 && k == CH - 1) {
                #pragma unroll
                for (int q = 0; q < 8; ++q) {
                    const int c = q >> 2, j = q & 3;
                    out[(size_t)(grow0 + rq * 4 + j) * 512 + d * 256 + (ct0 + c) * 16 + colw] = hv[q];
                }
            }

            if constexpr (L < 2) { anp0 = an0; anp1 = an1; }

            __builtin_amdgcn_sched_barrier(0);
            asm volatile("s_waitcnt lgkmcnt(0)" ::: "memory");
            __builtin_amdgcn_s_barrier();
            __builtin_amdgcn_sched_barrier(0);
        }
    }

    if constexpr (L < 2) {
        {   // emit slot CH-2
            uint4 sv;
            sv.x = pk2(anp0[0], anp0[1]); sv.y = pk2(anp0[2], anp0[3]);
            sv.z = pk2(anp1[0], anp1[1]); sv.w = pk2(anp1[2], anp1[3]);
            *(uint4*)(zdst + (size_t)(CH - 2) * ZTILE + zoff) = sv;
        }
        // tail: slot CH-1 from final h (buffer 1)
        f32x4 an0 = (f32x4){bn0, bn0, bn0, bn0};
        f32x4 an1 = (f32x4){bn1, bn1, bn1, bn1};
        #pragma unroll
        for (int kt = 0; kt < 8; ++kt) {
            const f16x8 ah = *(const f16x8*)&Hb[(1 << 12) + swz(colw, kt * 32 + rq8)];
            an0 = __builtin_amdgcn_mfma_f32_16x16x32_f16(ah, wn0[kt], an0, 0, 0, 0);
            an1 = __builtin_amdgcn_mfma_f32_16x16x32_f16(ah, wn1[kt], an1, 0, 0, 0);
        }
        uint4 sv;
        sv.x = pk2(an0[0], an0[1]); sv.y = pk2(an0[2], an0[3]);
        sv.z = pk2(an1[0], an1[1]); sv.w = pk2(an1[2], an1[3]);
        *(uint4*)(zdst + (size_t)(CH - 1) * ZTILE + zoff) = sv;
    }
    {   // h carry out (final h in buffer 1; CH even)
        uint16_t* hc = hcarry + (size_t)(d * 3 + L) * 131072;
        const int row = tid >> 5, c8 = (tid & 31) * 8;
        *(uint4*)(hc + (size_t)(grow0 + row) * 256 + c8) =
            *(const uint4*)&Hb[4096 + ((row * 256 + c8) ^ ((row & 7) << 3))];
    }
}

// ---------------- combined slot kernel: 192 rec blocks + 128 gemm0 blocks ----------------
__global__ __attribute__((amdgpu_flat_work_group_size(NT, NT), amdgpu_waves_per_eu(2)))
void rnn_slot(const float* x, const _Float16* wf0,
              const _Float16* whh_all, const _Float16* wihn_all,
              uint16_t* z0, uint16_t* z1, uint16_t* z2,
              uint16_t* hcarry, const float* fb, const float* bb,
              float* out, int slot)
{
    __shared__ uint16_t SH[2 * XLBUF];     // 21.2 KB; rec uses first 16 KB
    if (blockIdx.x < 192) {
        const int l = blockIdx.x >> 6, sub = blockIdx.x & 63;
        const int d = sub >> 5, i = sub & 31;
        const int cs = slot - l;
        if (cs < 0 || cs >= NCH) return;
        const size_t ringE = (size_t)((cs & 1) * 2 + d) * RING_E;
        if (l == 0) {
            const uint16_t* zs = z0 + ((size_t)d * SEQ + (size_t)cs * CH) * ZTILE;
            rec_run<0>(whh_all, wihn_all, zs, z1 + ringE, hcarry, fb, bb, out, d, i, cs, SH);
        } else if (l == 1) {
            rec_run<1>(whh_all, wihn_all, z1 + ringE, z2 + ringE, hcarry, fb, bb, out, d, i, cs, SH);
        } else {
            rec_run<2>(whh_all, wihn_all, z2 + ringE, nullptr, hcarry, fb, bb, out, d, i, cs, SH);
        }
    } else {
        const int chunk = slot + 1;        // produced for NEXT slot
        if (chunk < 0 || chunk >= NCH) return;
        gemm0_chunk(x, wf0, fb, bb, z0, chunk, blockIdx.x - 192, SH);
    }
}

extern "C" void kernel_launch(void* const* d_in, const int* in_sizes, int n_in,
                              void* d_out, int out_size, void* d_ws, size_t ws_size,
                              hipStream_t stream)
{
    (void)in_sizes; (void)n_in; (void)out_size; (void)ws_size;
    const float* x      = (const float*)d_in[0];
    const float* fW_ih0 = (const float*)d_in[1];
    const float* fW_ih  = (const float*)d_in[2];
    const float* fW_hh  = (const float*)d_in[3];
    const float* fb     = (const float*)d_in[4];
    const float* bW_ih0 = (const float*)d_in[5];
    const float* bW_ih  = (const float*)d_in[6];
    const float* bW_hh  = (const float*)d_in[7];
    const float* bb     = (const float*)d_in[8];
    uint8_t* ws = (uint8_t*)d_ws;

    _Float16* wf     = (_Float16*)ws;
    uint16_t* hcarry = (uint16_t*)(ws + HC_BYTE);
    uint16_t* z0     = (uint16_t*)(ws + Z0_BYTE);
    uint16_t* z1     = (uint16_t*)(ws + Z1_BYTE);
    uint16_t* z2     = (uint16_t*)(ws + Z2_BYTE);
    const _Float16* whh  = wf + WHH_E;
    const _Float16* wihn = wf + WIHN_E;
    float* out = (float*)d_out;

    rnn_prep<<<400, 256, 0, stream>>>(fW_ih0, fW_ih, fW_hh, bW_ih0, bW_ih, bW_hh, wf);
    for (int s = -1; s <= 9; ++s)
        rnn_slot<<<320, NT, 0, stream>>>(x, wf, whh, wihn, z0, z1, z2, hcarry, fb, bb, out, s);
}

// Round 14
// 734.881 us; speedup vs baseline: 1.3490x; 1.3490x over previous
//
#include <hip/hip_runtime.h>
#include <cstdint>
#include <cstddef>

// Bidirectional 3-layer tanh RNN, S=512 B=512 D=300 H=256.
// R14: best-of recombination. Separate launches (no co-schedule contention):
//      prep + gemm0 (R9 reg-pipelined form, 1024 blocks, ~152us) +
//      10 x rec slots (R12 form: unroll-4 true z prefetch, asm-pinned weights,
//      XOR-swizzled LDS h, lane-chunked z, lgkm-only barrier; 55.7us/slot).

#define SEQ   512
#define BATCH 512
#define DIN   300
#define HDIM  256
#define NT    512
#define CH    64
#define NCH   (SEQ / CH)    // 8
#define NSLOT (NCH + 2)     // 10
#define TS    16
#define ZTILE 131072        // u16 per (d,t) tile (512 rows x 256 cols)

typedef _Float16 f16x8 __attribute__((ext_vector_type(8)));
typedef __fp16   fp16x2 __attribute__((ext_vector_type(2)));
typedef float    f32x4 __attribute__((ext_vector_type(4)));

// ---- ws layout ----
#define WIH0_E 0            // f16 [2 dir][16ct][10kt][64][8]
#define WHH_E  163840       // f16 [2][3 layer][16ct][8kt][64][8]
#define WIHN_E 557056       // f16 [2][2 (->l1,l2)][16ct][8kt][64][8]
#define HC_BYTE   1638400   // u16 [2d][3l][512][256]
#define HB_BYTE   3211264
#define Z0_BYTE   (HB_BYTE + 67108864)
#define Z1_BYTE   (Z0_BYTE + 268435456)
#define Z2_BYTE   (Z1_BYTE + 67108864)
#define RING_E    8388608ull   // u16 per ring region (CH tiles)

static __device__ __forceinline__ uint16_t f16bits(_Float16 h) {
    union { _Float16 h; uint16_t u; } v; v.h = h; return v.u;
}
static __device__ __forceinline__ uint32_t pk2(float a, float b) {
    union { fp16x2 h; uint32_t u; } v; v.h = __builtin_amdgcn_cvt_pkrtz(a, b); return v.u;
}
static __device__ __forceinline__ int swz(int row, int col) {   // u16-index swizzle
    return (row * 256 + col) ^ ((row & 7) << 3);
}

// 8 fragment loads in one volatile asm (results CANNOT be rematerialized).
static __device__ __forceinline__ void aload8(f16x8 r[8], const _Float16* p, size_t stepE) {
    const _Float16* p0 = p;
    const _Float16* p1 = p + stepE;
    const _Float16* p2 = p + 2 * stepE;
    const _Float16* p3 = p + 3 * stepE;
    const _Float16* p4 = p + 4 * stepE;
    const _Float16* p5 = p + 5 * stepE;
    const _Float16* p6 = p + 6 * stepE;
    const _Float16* p7 = p + 7 * stepE;
    asm volatile(
        "global_load_dwordx4 %0, %8, off\n\t"
        "global_load_dwordx4 %1, %9, off\n\t"
        "global_load_dwordx4 %2, %10, off\n\t"
        "global_load_dwordx4 %3, %11, off\n\t"
        "global_load_dwordx4 %4, %12, off\n\t"
        "global_load_dwordx4 %5, %13, off\n\t"
        "global_load_dwordx4 %6, %14, off\n\t"
        "global_load_dwordx4 %7, %15, off"
        : "=&v"(r[0]), "=&v"(r[1]), "=&v"(r[2]), "=&v"(r[3]),
          "=&v"(r[4]), "=&v"(r[5]), "=&v"(r[6]), "=&v"(r[7])
        : "v"(p0), "v"(p1), "v"(p2), "v"(p3), "v"(p4), "v"(p5), "v"(p6), "v"(p7)
        : "memory");
}
static __device__ __forceinline__ void adrain() {
    asm volatile("s_waitcnt vmcnt(0)" ::: "memory");
    __builtin_amdgcn_sched_barrier(0);
}

// ---------------- prep: weights -> f16 fragment layout ----------------
__global__ void rnn_prep(const float* __restrict__ fW_ih0, const float* __restrict__ fW_ih,
                         const float* __restrict__ fW_hh,  const float* __restrict__ bW_ih0,
                         const float* __restrict__ bW_ih,  const float* __restrict__ bW_hh,
                         _Float16* __restrict__ wf)
{
    const int gid = blockIdx.x * 256 + threadIdx.x;   // 0..102399
    const int d = gid / 51200;
    const int r = gid - d * 51200;
    const int lane = r & 63;
    const float* Wih0 = d ? bW_ih0 : fW_ih0;
    const float* Wih  = d ? bW_ih  : fW_ih;
    const float* Whh  = d ? bW_hh  : fW_hh;
    _Float16 vals[8];
    size_t dstE;
    if (r < 10240) {                       // W_ih0 frags, K=320 padded
        const int ck = r >> 6, ct = ck / 10, kt = ck - ct * 10;
        const int col = ct * 16 + (lane & 15);
        const int k0  = kt * 32 + (lane >> 4) * 8;
        #pragma unroll
        for (int e = 0; e < 8; ++e) {
            const int k = k0 + e;
            vals[e] = (k < 300) ? (_Float16)Wih0[(size_t)k * 256 + col] : (_Float16)0.f;
        }
        dstE = (size_t)WIH0_E + (size_t)d * 81920 + (size_t)r * 8;
    } else if (r < 34816) {                // W_hh frags
        const int rr = r - 10240, l = rr / 8192, r2 = rr - l * 8192;
        const int ck = r2 >> 6, ct = ck >> 3, kt = ck & 7;
        const int col = ct * 16 + (lane & 15);
        const int k0  = kt * 32 + (lane >> 4) * 8;
        #pragma unroll
        for (int e = 0; e < 8; ++e)
            vals[e] = (_Float16)Whh[((size_t)(l * 256 + k0 + e)) * 256 + col];
        dstE = (size_t)WHH_E + (size_t)(d * 3 + l) * 65536 + (size_t)r2 * 8;
    } else {                               // W_ih layers 1,2 frags
        const int rr = r - 34816, ln = rr / 8192, r2 = rr - ln * 8192;
        const int ck = r2 >> 6, ct = ck >> 3, kt = ck & 7;
        const int col = ct * 16 + (lane & 15);
        const int k0  = kt * 32 + (lane >> 4) * 8;
        #pragma unroll
        for (int e = 0; e < 8; ++e)
            vals[e] = (_Float16)Wih[((size_t)(ln * 256 + k0 + e)) * 256 + col];
        dstE = (size_t)WIHN_E + (size_t)(d * 2 + ln) * 65536 + (size_t)r2 * 8;
    }
    *(f16x8*)(wf + dstE) = *(const f16x8*)vals;
}

// ---------------- gemm0: Zin0 = x @ W_ih0 + b0 (R9 proven form) ----------------
// 1024 blocks = 32 sg x 32 rb(16 rows), both dirs, TS=16 steps each.
__global__ __attribute__((amdgpu_flat_work_group_size(NT, NT)))
void rnn_gemm0(const float* __restrict__ x, const _Float16* __restrict__ wih0,
               const float* __restrict__ fb, const float* __restrict__ bb,
               uint16_t* __restrict__ z0)
{
    __shared__ uint16_t Xl[2][16 * 332];
    const int tid = threadIdx.x, lane = tid & 63, w = tid >> 6;
    const int colw = lane & 15, rq = lane >> 4, rq8 = rq * 8;
    const int ct0 = w * 2;
    const int sg = blockIdx.x >> 5, rb = blockIdx.x & 31;
    const int b0 = rb * 16;
    const size_t chunk = ((size_t)(rb * 8 + w) * 64 + lane) * 8;

    int rs[5], cc2[5]; bool pv[5];
    #pragma unroll
    for (int b = 0; b < 5; ++b) {
        const int p = tid + b * NT;
        pv[b] = p < 2400;
        const int r = p / 150;
        rs[b] = r; cc2[b] = (p - r * 150) * 2;
    }

    float bv[2][2];
    #pragma unroll
    for (int dd = 0; dd < 2; ++dd)
        #pragma unroll
        for (int c = 0; c < 2; ++c)
            bv[dd][c] = (dd ? bb : fb)[(ct0 + c) * 16 + colw];

    for (int p = tid; p < 320; p += NT) {
        const int bu = p / 160, q = p - bu * 160;
        const int r = q / 10, cc = 300 + (q - r * 10) * 2;
        *(uint32_t*)&Xl[bu][r * 332 + cc] = 0;
    }
    {
        const float* xs = x + ((size_t)(sg * TS) * BATCH + b0) * DIN;
        #pragma unroll
        for (int b = 0; b < 5; ++b) if (pv[b]) {
            const float2 v = *(const float2*)(xs + (size_t)rs[b] * DIN + cc2[b]);
            *(uint32_t*)&Xl[0][rs[b] * 332 + cc2[b]] = pk2(v.x, v.y);
        }
    }
    __syncthreads();

    #pragma unroll 1
    for (int si = 0; si < TS; ++si) {
        const int s = sg * TS + si;
        const int buf = si & 1;
        const bool last = (si == TS - 1);

        {   // dir 0
            f32x4 a0 = (f32x4){bv[0][0], bv[0][0], bv[0][0], bv[0][0]};
            f32x4 a1 = (f32x4){bv[0][1], bv[0][1], bv[0][1], bv[0][1]};
            #pragma unroll
            for (int kt = 0; kt < 10; ++kt) {
                const f16x8 wv0 = *(const f16x8*)(wih0 + (((size_t)ct0 * 10 + kt) * 64 + lane) * 8);
                const f16x8 wv1 = *(const f16x8*)(wih0 + (((size_t)(ct0 + 1) * 10 + kt) * 64 + lane) * 8);
                const f16x8 a = *(const f16x8*)&Xl[buf][colw * 332 + kt * 32 + rq8];
                a0 = __builtin_amdgcn_mfma_f32_16x16x32_f16(a, wv0, a0, 0, 0, 0);
                a1 = __builtin_amdgcn_mfma_f32_16x16x32_f16(a, wv1, a1, 0, 0, 0);
            }
            uint4 sv;
            sv.x = pk2(a0[0], a0[1]); sv.y = pk2(a0[2], a0[3]);
            sv.z = pk2(a1[0], a1[1]); sv.w = pk2(a1[2], a1[3]);
            *(uint4*)(z0 + (size_t)s * ZTILE + chunk) = sv;
        }

        float2 xr[5];
        if (!last) {
            const float* xs = x + ((size_t)(s + 1) * BATCH + b0) * DIN;
            #pragma unroll
            for (int b = 0; b < 5; ++b) if (pv[b])
                xr[b] = *(const float2*)(xs + (size_t)rs[b] * DIN + cc2[b]);
        }

        {   // dir 1
            f32x4 a0 = (f32x4){bv[1][0], bv[1][0], bv[1][0], bv[1][0]};
            f32x4 a1 = (f32x4){bv[1][1], bv[1][1], bv[1][1], bv[1][1]};
            #pragma unroll
            for (int kt = 0; kt < 10; ++kt) {
                const f16x8 wv0 = *(const f16x8*)(wih0 + 81920 + (((size_t)ct0 * 10 + kt) * 64 + lane) * 8);
                const f16x8 wv1 = *(const f16x8*)(wih0 + 81920 + (((size_t)(ct0 + 1) * 10 + kt) * 64 + lane) * 8);
                const f16x8 a = *(const f16x8*)&Xl[buf][colw * 332 + kt * 32 + rq8];
                a0 = __builtin_amdgcn_mfma_f32_16x16x32_f16(a, wv0, a0, 0, 0, 0);
                a1 = __builtin_amdgcn_mfma_f32_16x16x32_f16(a, wv1, a1, 0, 0, 0);
            }
            uint4 sv;
            sv.x = pk2(a0[0], a0[1]); sv.y = pk2(a0[2], a0[3]);
            sv.z = pk2(a1[0], a1[1]); sv.w = pk2(a1[2], a1[3]);
            *(uint4*)(z0 + ((size_t)SEQ + (SEQ - 1 - s)) * ZTILE + chunk) = sv;
        }

        if (!last) {
            #pragma unroll
            for (int b = 0; b < 5; ++b) if (pv[b])
                *(uint32_t*)&Xl[buf ^ 1][rs[b] * 332 + cc2[b]] = pk2(xr[b].x, xr[b].y);
        }

        __builtin_amdgcn_sched_barrier(0);
        asm volatile("s_waitcnt lgkmcnt(0)" ::: "memory");
        __builtin_amdgcn_s_barrier();
        __builtin_amdgcn_sched_barrier(0);
    }
}

// ---------------- fused rec<L>: unroll-4, true 4-deep z prefetch (R12) ----------------
template<int L>
__device__ __forceinline__ void rec_run(const _Float16* whh_all, const _Float16* wihn_all,
                                        const uint16_t* zsrc, uint16_t* zdst,
                                        uint16_t* hcarry, const float* fb, const float* bb,
                                        float* out, int d, int i, int cs, uint16_t* Hb)
{
    const int tid = threadIdx.x, lane = tid & 63, w = tid >> 6;
    const int colw = lane & 15, rq = lane >> 4, rq8 = rq * 8;
    const int ct0 = w * 2;
    const int grow0 = i * 16;

    // ---- weights: asm-pinned, single drain ----
    const _Float16* whh = whh_all + (size_t)(d * 3 + L) * 65536;
    f16x8 wh0[8], wh1[8];
    aload8(wh0, whh + ((size_t)ct0 * 8 * 64 + lane) * 8, 512);
    aload8(wh1, whh + ((size_t)(ct0 + 1) * 8 * 64 + lane) * 8, 512);
    f16x8 wn0[8], wn1[8];
    float bn0 = 0.f, bn1 = 0.f;
    if constexpr (L < 2) {
        const _Float16* wnx = wihn_all + (size_t)(d * 2 + L) * 65536;
        aload8(wn0, wnx + ((size_t)ct0 * 8 * 64 + lane) * 8, 512);
        aload8(wn1, wnx + ((size_t)(ct0 + 1) * 8 * 64 + lane) * 8, 512);
        const float* bnx = (d ? bb : fb) + (L + 1) * HDIM;
        bn0 = bnx[ct0 * 16 + colw];
        bn1 = bnx[(ct0 + 1) * 16 + colw];
    }
    adrain();

    // ---- init h LDS (zero; carry into buffer 1, swizzled) ----
    for (int p = tid; p < 4096; p += NT) ((uint32_t*)Hb)[p] = 0;
    __syncthreads();
    if (cs > 0) {
        const uint16_t* hc = hcarry + (size_t)(d * 3 + L) * 131072;
        const int row = tid >> 5, c8 = (tid & 31) * 8;
        *(uint4*)&Hb[4096 + ((row * 256 + c8) ^ ((row & 7) << 3))] =
            *(const uint4*)(hc + (size_t)(grow0 + row) * 256 + c8);
    }
    __syncthreads();

    const size_t zoff = ((size_t)(i * 8 + w) * 64 + lane) * 8;

    uint4 zp[4];
    #pragma unroll
    for (int j = 0; j < 4; ++j)
        zp[j] = *(const uint4*)(zsrc + (size_t)j * ZTILE + zoff);

    f32x4 anp0 = {}, anp1 = {};

    #pragma unroll 1
    for (int k0 = 0; k0 < CH; k0 += 4) {
        #pragma unroll
        for (int u = 0; u < 4; ++u) {
            const int k = k0 + u;
            const int cur = u & 1, prv = cur ^ 1;   // k0 multiple of 4 -> k&1 == u&1

            // C-init = z(k) (loaded 4 sub-steps ago; static index)
            f32x4 ar0, ar1;
            {
                union { uint4 v; _Float16 h[8]; } zz; zz.v = zp[u];
                ar0 = (f32x4){(float)zz.h[0], (float)zz.h[1], (float)zz.h[2], (float)zz.h[3]};
                ar1 = (f32x4){(float)zz.h[4], (float)zz.h[5], (float)zz.h[6], (float)zz.h[7]};
            }
            {   // issue reload for k+4
                const int kp = (k + 4 < CH) ? (k + 4) : (CH - 1);
                zp[u] = *(const uint4*)(zsrc + (size_t)kp * ZTILE + zoff);
            }

            f16x8 ah[8];
            #pragma unroll
            for (int kt = 0; kt < 8; ++kt)
                ah[kt] = *(const f16x8*)&Hb[(prv << 12) + swz(colw, kt * 32 + rq8)];

            f32x4 an0, an1;
            if constexpr (L < 2) {
                an0 = (f32x4){bn0, bn0, bn0, bn0};
                an1 = (f32x4){bn1, bn1, bn1, bn1};
                #pragma unroll
                for (int kt = 0; kt < 8; ++kt) {       // 4 interleaved chains
                    ar0 = __builtin_amdgcn_mfma_f32_16x16x32_f16(ah[kt], wh0[kt], ar0, 0, 0, 0);
                    ar1 = __builtin_amdgcn_mfma_f32_16x16x32_f16(ah[kt], wh1[kt], ar1, 0, 0, 0);
                    an0 = __builtin_amdgcn_mfma_f32_16x16x32_f16(ah[kt], wn0[kt], an0, 0, 0, 0);
                    an1 = __builtin_amdgcn_mfma_f32_16x16x32_f16(ah[kt], wn1[kt], an1, 0, 0, 0);
                }
            } else {
                f32x4 arB0 = {}, arB1 = {};
                #pragma unroll
                for (int kt = 0; kt < 4; ++kt) {
                    ar0  = __builtin_amdgcn_mfma_f32_16x16x32_f16(ah[kt],     wh0[kt],     ar0,  0, 0, 0);
                    ar1  = __builtin_amdgcn_mfma_f32_16x16x32_f16(ah[kt],     wh1[kt],     ar1,  0, 0, 0);
                    arB0 = __builtin_amdgcn_mfma_f32_16x16x32_f16(ah[4 + kt], wh0[4 + kt], arB0, 0, 0, 0);
                    arB1 = __builtin_amdgcn_mfma_f32_16x16x32_f16(ah[4 + kt], wh1[4 + kt], arB1, 0, 0, 0);
                }
                ar0 = ar0 + arB0;
                ar1 = ar1 + arB1;
            }

            // emit Zin_next(k-2) in the MFMA shadow
            if constexpr (L < 2) {
                if (k >= 2) {
                    uint4 sv;
                    sv.x = pk2(anp0[0], anp0[1]); sv.y = pk2(anp0[2], anp0[3]);
                    sv.z = pk2(anp1[0], anp1[1]); sv.w = pk2(anp1[2], anp1[3]);
                    *(uint4*)(zdst + (size_t)(k - 2) * ZTILE + zoff) = sv;
                }
            }

            float hv[8];
            #pragma unroll
            for (int q = 0; q < 8; ++q) {
                const float S = (q < 4) ? ar0[q] : ar1[q - 4];
                const float e = __builtin_amdgcn_exp2f(S * 2.885390081777927f);
                const float r = __builtin_amdgcn_rcpf(e + 1.f);
                hv[q] = __builtin_fmaf(-2.f, r, 1.f);
            }
            #pragma unroll
            for (int q = 0; q < 8; ++q) {
                const int c = q >> 2, j = q & 3;
                Hb[(cur << 12) + swz(rq * 4 + j, (ct0 + c) * 16 + colw)] = f16bits((_Float16)hv[q]);
            }
            if (L == 2 && cs == NCH - 1 && k == CH - 1) {
                #pragma unroll
                for (int q = 0; q < 8; ++q) {
                    const int c = q >> 2, j = q & 3;
                    out[(size_t)(grow0 + rq * 4 + j) * 512 + d * 256 + (ct0 + c) * 16 + colw] = hv[q];
                }
            }

            if constexpr (L < 2) { anp0 = an0; anp1 = an1; }

            __builtin_amdgcn_sched_barrier(0);
            asm volatile("s_waitcnt lgkmcnt(0)" ::: "memory");
            __builtin_amdgcn_s_barrier();
            __builtin_amdgcn_sched_barrier(0);
        }
    }

    if constexpr (L < 2) {
        {   // emit slot CH-2 (anp = an of step CH-1)
            uint4 sv;
            sv.x = pk2(anp0[0], anp0[1]); sv.y = pk2(anp0[2], anp0[3]);
            sv.z = pk2(anp1[0], anp1[1]); sv.w = pk2(anp1[2], anp1[3]);
            *(uint4*)(zdst + (size_t)(CH - 2) * ZTILE + zoff) = sv;
        }
        // tail: slot CH-1 from final h (buffer 1)
        f32x4 an0 = (f32x4){bn0, bn0, bn0, bn0};
        f32x4 an1 = (f32x4){bn1, bn1, bn1, bn1};
        #pragma unroll
        for (int kt = 0; kt < 8; ++kt) {
            const f16x8 ah = *(const f16x8*)&Hb[(1 << 12) + swz(colw, kt * 32 + rq8)];
            an0 = __builtin_amdgcn_mfma_f32_16x16x32_f16(ah, wn0[kt], an0, 0, 0, 0);
            an1 = __builtin_amdgcn_mfma_f32_16x16x32_f16(ah, wn1[kt], an1, 0, 0, 0);
        }
        uint4 sv;
        sv.x = pk2(an0[0], an0[1]); sv.y = pk2(an0[2], an0[3]);
        sv.z = pk2(an1[0], an1[1]); sv.w = pk2(an1[2], an1[3]);
        *(uint4*)(zdst + (size_t)(CH - 1) * ZTILE + zoff) = sv;
    }
    {   // h carry out (final h in buffer 1; CH even)
        uint16_t* hc = hcarry + (size_t)(d * 3 + L) * 131072;
        const int row = tid >> 5, c8 = (tid & 31) * 8;
        *(uint4*)(hc + (size_t)(grow0 + row) * 256 + c8) =
            *(const uint4*)&Hb[4096 + ((row * 256 + c8) ^ ((row & 7) << 3))];
    }
}

__global__ __attribute__((amdgpu_flat_work_group_size(NT, NT), amdgpu_waves_per_eu(2)))
void rnn_rec(const _Float16* whh_all, const _Float16* wihn_all,
             uint16_t* z0, uint16_t* z1, uint16_t* z2,
             uint16_t* hcarry, const float* fb, const float* bb,
             float* out, int slot)
{
    __shared__ uint16_t Hb[2 * 4096];
    const int l = blockIdx.x >> 6, sub = blockIdx.x & 63;
    const int d = sub >> 5, i = sub & 31;
    const int cs = slot - l;
    if (cs < 0 || cs >= NCH) return;
    const size_t ringE = (size_t)((cs & 1) * 2 + d) * RING_E;
    if (l == 0) {
        const uint16_t* zs = z0 + ((size_t)d * SEQ + (size_t)cs * CH) * ZTILE;
        rec_run<0>(whh_all, wihn_all, zs, z1 + ringE, hcarry, fb, bb, out, d, i, cs, Hb);
    } else if (l == 1) {
        rec_run<1>(whh_all, wihn_all, z1 + ringE, z2 + ringE, hcarry, fb, bb, out, d, i, cs, Hb);
    } else {
        rec_run<2>(whh_all, wihn_all, z2 + ringE, nullptr, hcarry, fb, bb, out, d, i, cs, Hb);
    }
}

extern "C" void kernel_launch(void* const* d_in, const int* in_sizes, int n_in,
                              void* d_out, int out_size, void* d_ws, size_t ws_size,
                              hipStream_t stream)
{
    (void)in_sizes; (void)n_in; (void)out_size; (void)ws_size;
    const float* x      = (const float*)d_in[0];
    const float* fW_ih0 = (const float*)d_in[1];
    const float* fW_ih  = (const float*)d_in[2];
    const float* fW_hh  = (const float*)d_in[3];
    const float* fb     = (const float*)d_in[4];
    const float* bW_ih0 = (const float*)d_in[5];
    const float* bW_ih  = (const float*)d_in[6];
    const float* bW_hh  = (const float*)d_in[7];
    const float* bb     = (const float*)d_in[8];
    uint8_t* ws = (uint8_t*)d_ws;

    _Float16* wf     = (_Float16*)ws;
    uint16_t* hcarry = (uint16_t*)(ws + HC_BYTE);
    uint16_t* z0     = (uint16_t*)(ws + Z0_BYTE);
    uint16_t* z1     = (uint16_t*)(ws + Z1_BYTE);
    uint16_t* z2     = (uint16_t*)(ws + Z2_BYTE);
    const _Float16* whh  = wf + WHH_E;
    const _Float16* wihn = wf + WIHN_E;
    float* out = (float*)d_out;

    rnn_prep<<<400, 256, 0, stream>>>(fW_ih0, fW_ih, fW_hh, bW_ih0, bW_ih, bW_hh, wf);
    rnn_gemm0<<<1024, NT, 0, stream>>>(x, wf, fb, bb, z0);
    for (int s = 0; s < NSLOT; ++s)
        rnn_rec<<<192, NT, 0, stream>>>(whh, wihn, z0, z1, z2, hcarry, fb, bb, out, s);
}